// Round 1
// baseline (790.098 us; speedup 1.0000x reference)
//
#include <hip/hip_runtime.h>
#include <math.h>

// Problem constants
#define BB   4
#define LL   4096
#define CC   512
#define GG   4
#define HH   16
#define KW   5      // conv kernel / offset range factor
#define GCC  128    // C / G
#define HCC  32     // C / H
#define BGN  (BB*GG)   // 16
#define BHN  (BB*HH)   // 64
#define KSPLIT 16

// ---------------------------------------------------------------------------
// Kernel 0: fuse the two offset convs (both linear, no activation between):
//   Wcomb[c',t] = sum_c Woff2[c] * Woff1[c,c',t]    (640 values)
//   wc[640] = sum_c Woff2[c]*boff1[c] + boff2       (bias for valid positions)
//   wc[641] = boff2                                  (bias when conv1 out is padding)
// ---------------------------------------------------------------------------
__global__ void comb_weights(const float* __restrict__ Woff1, const float* __restrict__ boff1,
                             const float* __restrict__ Woff2, const float* __restrict__ boff2,
                             float* __restrict__ wc)
{
    int idx = blockIdx.x * 256 + threadIdx.x;
    if (idx < GCC * KW) {
        int cp = idx / KW, t = idx - cp * KW;
        float s = 0.f;
        for (int c = 0; c < GCC; ++c)
            s = fmaf(Woff2[c], Woff1[((size_t)c * GCC + cp) * KW + t], s);
        wc[idx] = s;
    } else if (idx == GCC * KW) {
        float s = boff2[0];
        for (int c = 0; c < GCC; ++c) s = fmaf(Woff2[c], boff1[c], s);
        wc[idx] = s;
    } else if (idx == GCC * KW + 1) {
        wc[idx] = boff2[0];
    }
}

// ---------------------------------------------------------------------------
// Generic NT GEMM:  out[b][m][n] = sum_k A[m,k] * Bm[b][n,k] + bias[m]
//   A: [M,K] row-major (shared over batch), Bm: [NB,N,K] row-major
//   mode 0: out[(b*M+m)*N+n]  (+ rpb[m*N+n] if rpb != null)
//   mode 1: out[(b*N+n)*M+m]  (transposed write, for the final projection)
// 128x128 block tile, BK=16, 256 threads, 8x8 micro-tile (split 2x 4-wide).
// ---------------------------------------------------------------------------
__global__ __launch_bounds__(256) void gemm_nt_kernel(
    const float* __restrict__ A, const float* __restrict__ Bm,
    const float* __restrict__ bias, const float* __restrict__ rpb,
    float* __restrict__ out, int M, int N, int Kd, int mode)
{
    const int b  = blockIdx.z;
    const int n0 = blockIdx.x * 128;
    const int m0 = blockIdx.y * 128;
    const float* Bb = Bm + (size_t)b * N * Kd;

    __shared__ float As[16][132];
    __shared__ float Bs[16][132];

    const int tid  = threadIdx.x;
    const int tx   = tid & 15;
    const int ty   = tid >> 4;
    const int lrow = tid >> 1;        // 0..127
    const int lk   = (tid & 1) * 8;   // 0 or 8

    const float* Ap = A  + (size_t)(m0 + lrow) * Kd + lk;
    const float* Bp = Bb + (size_t)(n0 + lrow) * Kd + lk;

    float acc[8][8];
#pragma unroll
    for (int i = 0; i < 8; ++i)
#pragma unroll
        for (int j = 0; j < 8; ++j) acc[i][j] = 0.f;

    for (int k0 = 0; k0 < Kd; k0 += 16) {
        float4 a0 = *(const float4*)(Ap + k0);
        float4 a1 = *(const float4*)(Ap + k0 + 4);
        float4 b0 = *(const float4*)(Bp + k0);
        float4 b1 = *(const float4*)(Bp + k0 + 4);
        __syncthreads();
        As[lk+0][lrow] = a0.x; As[lk+1][lrow] = a0.y; As[lk+2][lrow] = a0.z; As[lk+3][lrow] = a0.w;
        As[lk+4][lrow] = a1.x; As[lk+5][lrow] = a1.y; As[lk+6][lrow] = a1.z; As[lk+7][lrow] = a1.w;
        Bs[lk+0][lrow] = b0.x; Bs[lk+1][lrow] = b0.y; Bs[lk+2][lrow] = b0.z; Bs[lk+3][lrow] = b0.w;
        Bs[lk+4][lrow] = b1.x; Bs[lk+5][lrow] = b1.y; Bs[lk+6][lrow] = b1.z; Bs[lk+7][lrow] = b1.w;
        __syncthreads();
#pragma unroll
        for (int kk = 0; kk < 16; ++kk) {
            float af[8], bf[8];
            float4 t0 = *(const float4*)(&As[kk][ty * 4]);
            float4 t1 = *(const float4*)(&As[kk][64 + ty * 4]);
            float4 u0 = *(const float4*)(&Bs[kk][tx * 4]);
            float4 u1 = *(const float4*)(&Bs[kk][64 + tx * 4]);
            af[0]=t0.x; af[1]=t0.y; af[2]=t0.z; af[3]=t0.w;
            af[4]=t1.x; af[5]=t1.y; af[6]=t1.z; af[7]=t1.w;
            bf[0]=u0.x; bf[1]=u0.y; bf[2]=u0.z; bf[3]=u0.w;
            bf[4]=u1.x; bf[5]=u1.y; bf[6]=u1.z; bf[7]=u1.w;
#pragma unroll
            for (int i = 0; i < 8; ++i)
#pragma unroll
                for (int j = 0; j < 8; ++j)
                    acc[i][j] = fmaf(af[i], bf[j], acc[i][j]);
        }
    }

    if (mode == 0) {
        float* ob = out + (size_t)b * M * N;
#pragma unroll
        for (int i = 0; i < 8; ++i) {
            int m = m0 + (i >> 2) * 64 + ty * 4 + (i & 3);
            float bi = bias[m];
#pragma unroll
            for (int jh = 0; jh < 2; ++jh) {
                int n = n0 + jh * 64 + tx * 4;
                float4 r = make_float4(acc[i][jh*4+0] + bi, acc[i][jh*4+1] + bi,
                                       acc[i][jh*4+2] + bi, acc[i][jh*4+3] + bi);
                if (rpb) {
                    float4 p = *(const float4*)(rpb + (size_t)m * N + n);
                    r.x += p.x; r.y += p.y; r.z += p.z; r.w += p.w;
                }
                *(float4*)(ob + (size_t)m * N + n) = r;
            }
        }
    } else {
        float* ob = out + (size_t)b * (size_t)N * M;
        float4 c0 = *(const float4*)(bias + m0 + ty * 4);
        float4 c1 = *(const float4*)(bias + m0 + 64 + ty * 4);
#pragma unroll
        for (int j = 0; j < 8; ++j) {
            int n = n0 + (j >> 2) * 64 + tx * 4 + (j & 3);
            float4 r0 = make_float4(acc[0][j] + c0.x, acc[1][j] + c0.y,
                                    acc[2][j] + c0.z, acc[3][j] + c0.w);
            float4 r1 = make_float4(acc[4][j] + c1.x, acc[5][j] + c1.y,
                                    acc[6][j] + c1.z, acc[7][j] + c1.w);
            *(float4*)(ob + (size_t)n * M + m0 + ty * 4)      = r0;
            *(float4*)(ob + (size_t)n * M + m0 + 64 + ty * 4) = r1;
        }
    }
}

// ---------------------------------------------------------------------------
// Kernel 2: fused offset prediction. For output position l (only l<L needed,
// since gather result is cropped to :L):
//   p = l-2 is conv1's position; p<0 -> conv2 sees zero-pad -> boff2 only.
//   valid: acc = sum_{c,t} Wcomb[c,t]*q[bg,c,l+t-4] + bcomb
//   off = tanh(acc)*5 ;  iy = (l+off)*(L/(N-1)) - 0.5   (N = L+4)
// Stores iy directly.
// ---------------------------------------------------------------------------
__global__ __launch_bounds__(256) void offsets_kernel(
    const float* __restrict__ q, const float* __restrict__ wc,
    float* __restrict__ offv)
{
    __shared__ float w[GCC * KW + 2];
    for (int i = threadIdx.x; i < GCC * KW + 2; i += 256) w[i] = wc[i];
    __syncthreads();

    int bg = blockIdx.y;
    int l  = blockIdx.x * 256 + threadIdx.x;
    const float* qb = q + (size_t)bg * GCC * LL;

    float acc;
    if (l < 2) {
        acc = w[GCC * KW + 1];           // conv1 output is zero-padding here
    } else {
        acc = w[GCC * KW];               // combined bias
        if (l >= 4) {                    // fast path: window fully in-bounds
            for (int cp = 0; cp < GCC; ++cp) {
                const float* qr = qb + (size_t)cp * LL + l - 4;
#pragma unroll
                for (int t = 0; t < KW; ++t)
                    acc = fmaf(w[cp * KW + t], qr[t], acc);
            }
        } else {                         // l in {2,3}: partial window
            for (int cp = 0; cp < GCC; ++cp) {
#pragma unroll
                for (int t = 0; t < KW; ++t) {
                    int ll2 = l + t - 4;
                    if (ll2 >= 0)
                        acc = fmaf(w[cp * KW + t], qb[(size_t)cp * LL + ll2], acc);
                }
            }
        }
    }
    float off = tanhf(acc) * (float)KW;
    float vg  = (float)l + off;
    float iy  = vg * ((float)LL / (float)(LL + 2 * (KW / 2) - 1)) - 0.5f;  // L/4099
    offv[(size_t)bg * LL + l] = iy;
}

// ---------------------------------------------------------------------------
// Kernel 3: bilinear gather. xg[bg,d,l] == x[b, l, g*GC+d], so for a fixed
// sample position the 128 channels are contiguous -> coalesced float4 both
// sides. Writes xs in [B, L, C] layout so the k/v GEMMs reuse gemm_nt.
// ---------------------------------------------------------------------------
__global__ __launch_bounds__(256) void gather_kernel(
    const float* __restrict__ x, const float* __restrict__ offv,
    float* __restrict__ xs)
{
    int bg = blockIdx.y;
    int b = bg >> 2, g = bg & 3;
    int l  = blockIdx.x * 8 + (threadIdx.x >> 5);
    int d4 = (threadIdx.x & 31) * 4;

    float iy = offv[(size_t)bg * LL + l];
    float fi = floorf(iy);
    float w1 = iy - fi;
    int i0 = (int)fi;
    int i1 = i0 + 1;

    const float* xb = x + (size_t)b * LL * CC + (size_t)g * GCC + d4;
    float4 v0 = make_float4(0.f, 0.f, 0.f, 0.f);
    float4 v1 = make_float4(0.f, 0.f, 0.f, 0.f);
    if (i0 >= 0 && i0 < LL) v0 = *(const float4*)(xb + (size_t)i0 * CC);
    if (i1 >= 0 && i1 < LL) v1 = *(const float4*)(xb + (size_t)i1 * CC);
    float w0 = 1.f - w1;
    float4 r = make_float4(v0.x * w0 + v1.x * w1, v0.y * w0 + v1.y * w1,
                           v0.z * w0 + v1.z * w1, v0.w * w0 + v1.w * w1);
    *(float4*)(xs + ((size_t)b * LL + l) * CC + g * GCC + d4) = r;
}

// ---------------------------------------------------------------------------
// Kernel 4: attention logits, split-K. One wave per (k-chunk, bh).
// 8x8 lanes, each lane a 4x4 (i,j) tile; q/k rows read straight from global
// (in-wave duplicate addresses merge; data is L2/L3 resident).
// part layout: [bh][ks][32][32]
// ---------------------------------------------------------------------------
__global__ __launch_bounds__(64) void qk_logits(
    const float* __restrict__ q, const float* __restrict__ k,
    float* __restrict__ part)
{
    int ks = blockIdx.x, bh = blockIdx.y;
    int b = bh >> 4, h = bh & 15;
    int lane = threadIdx.x;
    int ti = lane >> 3, tj = lane & 7;
    const float* qb = q + ((size_t)b * CC + h * HCC + ti * 4) * LL;
    const float* kb = k + ((size_t)b * CC + h * HCC + tj * 4) * LL;

    float acc[4][4];
#pragma unroll
    for (int i = 0; i < 4; ++i)
#pragma unroll
        for (int j = 0; j < 4; ++j) acc[i][j] = 0.f;

    const int chunk = LL / KSPLIT;   // 256
    int l0 = ks * chunk;
    for (int l = l0; l < l0 + chunk; l += 8) {
        float4 qa[4][2], kv[4][2];
#pragma unroll
        for (int p = 0; p < 4; ++p) {
            qa[p][0] = *(const float4*)(qb + (size_t)p * LL + l);
            qa[p][1] = *(const float4*)(qb + (size_t)p * LL + l + 4);
            kv[p][0] = *(const float4*)(kb + (size_t)p * LL + l);
            kv[p][1] = *(const float4*)(kb + (size_t)p * LL + l + 4);
        }
#pragma unroll
        for (int i = 0; i < 4; ++i)
#pragma unroll
            for (int j = 0; j < 4; ++j) {
                float s = acc[i][j];
                s = fmaf(qa[i][0].x, kv[j][0].x, s);
                s = fmaf(qa[i][0].y, kv[j][0].y, s);
                s = fmaf(qa[i][0].z, kv[j][0].z, s);
                s = fmaf(qa[i][0].w, kv[j][0].w, s);
                s = fmaf(qa[i][1].x, kv[j][1].x, s);
                s = fmaf(qa[i][1].y, kv[j][1].y, s);
                s = fmaf(qa[i][1].z, kv[j][1].z, s);
                s = fmaf(qa[i][1].w, kv[j][1].w, s);
                acc[i][j] = s;
            }
    }
#pragma unroll
    for (int i = 0; i < 4; ++i)
#pragma unroll
        for (int j = 0; j < 4; ++j)
            part[(((size_t)bh * KSPLIT + ks) * HCC + ti * 4 + i) * HCC + tj * 4 + j] = acc[i][j];
}

// ---------------------------------------------------------------------------
// Kernel 5: reduce split-K partials, scale, softmax over j. One block per bh,
// thread i handles row i.
// ---------------------------------------------------------------------------
__global__ __launch_bounds__(64) void softmax_kernel(
    const float* __restrict__ part, float* __restrict__ attn)
{
    int bh = blockIdx.x;
    int i = threadIdx.x;
    if (i >= HCC) return;
    const float SCALE = 0.044194173824159216f;  // 512^-0.5

    float lg[HCC];
    float mx = -1e30f;
#pragma unroll
    for (int j = 0; j < HCC; ++j) {
        float s = 0.f;
        for (int ks = 0; ks < KSPLIT; ++ks)
            s += part[(((size_t)bh * KSPLIT + ks) * HCC + i) * HCC + j];
        s *= SCALE;
        lg[j] = s;
        mx = fmaxf(mx, s);
    }
    float sum = 0.f;
#pragma unroll
    for (int j = 0; j < HCC; ++j) {
        float e = expf(lg[j] - mx);
        lg[j] = e;
        sum += e;
    }
    float inv = 1.f / sum;
#pragma unroll
    for (int j = 0; j < HCC; ++j)
        attn[((size_t)bh * HCC + i) * HCC + j] = lg[j] * inv;
}

// ---------------------------------------------------------------------------
// Kernel 6: o[bh,i,l] = sum_j attn[i,j] * v[bh,j,l], written directly in the
// final [B, L, C] layout (c = h*32+i) via a small LDS transpose so global
// writes are coalesced. attn row cached in registers. v read from global
// (per-instruction duplicate addresses merge; v is L2-resident).
// ---------------------------------------------------------------------------
__global__ __launch_bounds__(256) void attn_v_kernel(
    const float* __restrict__ attn, const float* __restrict__ v,
    float* __restrict__ o)
{
    int bh = blockIdx.y;
    int b = bh >> 4, h = bh & 15;
    int tid = threadIdx.x;
    int i = tid >> 3, lsub = tid & 7;

    float arow[HCC];
#pragma unroll
    for (int j = 0; j < HCC; ++j)
        arow[j] = attn[((size_t)bh * HCC + i) * HCC + j];

    const float* vb = v + ((size_t)b * CC + h * HCC) * LL;
    __shared__ float os[HCC][65];

    for (int l0 = blockIdx.x * 512; l0 < blockIdx.x * 512 + 512; l0 += 64) {
        int lbase = l0 + lsub * 8;
        float4 a0 = make_float4(0.f, 0.f, 0.f, 0.f);
        float4 a1 = make_float4(0.f, 0.f, 0.f, 0.f);
#pragma unroll 8
        for (int j = 0; j < HCC; ++j) {
            float aw = arow[j];
            float4 v0 = *(const float4*)(vb + (size_t)j * LL + lbase);
            float4 v1 = *(const float4*)(vb + (size_t)j * LL + lbase + 4);
            a0.x = fmaf(aw, v0.x, a0.x); a0.y = fmaf(aw, v0.y, a0.y);
            a0.z = fmaf(aw, v0.z, a0.z); a0.w = fmaf(aw, v0.w, a0.w);
            a1.x = fmaf(aw, v1.x, a1.x); a1.y = fmaf(aw, v1.y, a1.y);
            a1.z = fmaf(aw, v1.z, a1.z); a1.w = fmaf(aw, v1.w, a1.w);
        }
        os[i][lsub*8+0] = a0.x; os[i][lsub*8+1] = a0.y;
        os[i][lsub*8+2] = a0.z; os[i][lsub*8+3] = a0.w;
        os[i][lsub*8+4] = a1.x; os[i][lsub*8+5] = a1.y;
        os[i][lsub*8+6] = a1.z; os[i][lsub*8+7] = a1.w;
        __syncthreads();
        int i2 = tid & 31, lw = tid >> 5;
#pragma unroll
        for (int c = 0; c < 8; ++c) {
            int ll = lw * 8 + c;
            o[((size_t)b * LL + l0 + ll) * CC + h * HCC + i2] = os[i2][ll];
        }
        __syncthreads();
    }
}

// ---------------------------------------------------------------------------
extern "C" void kernel_launch(void* const* d_in, const int* in_sizes, int n_in,
                              void* d_out, int out_size, void* d_ws, size_t ws_size,
                              hipStream_t stream)
{
    (void)in_sizes; (void)n_in; (void)out_size; (void)ws_size;
    const float* x     = (const float*)d_in[0];
    const float* Wq    = (const float*)d_in[1];
    const float* bq    = (const float*)d_in[2];
    const float* Wk    = (const float*)d_in[3];
    const float* bk    = (const float*)d_in[4];
    const float* Wv    = (const float*)d_in[5];
    const float* bv    = (const float*)d_in[6];
    const float* Woff1 = (const float*)d_in[7];
    const float* boff1 = (const float*)d_in[8];
    const float* Woff2 = (const float*)d_in[9];
    const float* boff2 = (const float*)d_in[10];
    const float* rpb   = (const float*)d_in[11];
    const float* Wout  = (const float*)d_in[12];
    const float* bout  = (const float*)d_in[13];
    float* out = (float*)d_out;

    float* ws   = (float*)d_ws;
    float* q    = ws;                    // [B,C,L]     8,388,608
    float* xs   = ws + 8388608;          // [B,L,C]     8,388,608 (reused as o_final)
    float* kbuf = ws + 16777216;         // [B,C,L]     8,388,608
    float* vbuf = ws + 25165824;         // [B,C,L]     8,388,608
    float* offv = ws + 33554432;         // [BG,L]      65,536  (stores iy)
    float* wcmb = ws + 33619968;         // 642
    float* part = ws + 33620992;         // [64,16,32,32] 1,048,576
    float* attn = ws + 34669568;         // [64,32,32]  65,536
    // total: 34,735,104 floats = 138.9 MB

    comb_weights<<<dim3(3), dim3(256), 0, stream>>>(Woff1, boff1, Woff2, boff2, wcmb);
    // q = Wq @ x^T  -> [B,C,L]
    gemm_nt_kernel<<<dim3(32, 4, 4), dim3(256), 0, stream>>>(Wq, x, bq, nullptr, q, CC, LL, CC, 0);
    // fused offset convs -> iy per (bg, l)
    offsets_kernel<<<dim3(16, 16), dim3(256), 0, stream>>>(q, wcmb, offv);
    // bilinear gather -> xs [B,L,C]
    gather_kernel<<<dim3(512, 16), dim3(256), 0, stream>>>(x, offv, xs);
    // k, v projections (v adds rpb)
    gemm_nt_kernel<<<dim3(32, 4, 4), dim3(256), 0, stream>>>(Wk, xs, bk, nullptr, kbuf, CC, LL, CC, 0);
    gemm_nt_kernel<<<dim3(32, 4, 4), dim3(256), 0, stream>>>(Wv, xs, bv, rpb,    vbuf, CC, LL, CC, 0);
    // channel attention
    qk_logits<<<dim3(KSPLIT, BHN), dim3(64), 0, stream>>>(q, kbuf, part);
    softmax_kernel<<<dim3(BHN), dim3(64), 0, stream>>>(part, attn);
    attn_v_kernel<<<dim3(8, BHN), dim3(256), 0, stream>>>(attn, vbuf, xs /* o_final */);
    // out = o @ Wout^T + bout  -> [B,L,C]
    gemm_nt_kernel<<<dim3(128, 4, 1), dim3(256), 0, stream>>>(Wout, xs, bout, nullptr, out, CC, BB * LL, CC, 1);
}

// Round 2
// 465.608 us; speedup vs baseline: 1.6969x; 1.6969x over previous
//
#include <hip/hip_runtime.h>
#include <math.h>

// Problem constants
#define BB   4
#define LL   4096
#define CC   512
#define GG   4
#define HH   16
#define KW   5      // conv kernel / offset range factor
#define GCC  128    // C / G
#define HCC  32     // C / H
#define BGN  (BB*GG)   // 16
#define BHN  (BB*HH)   // 64
#define KSPLIT 16

typedef __attribute__((ext_vector_type(8))) __bf16 bf16x8;
typedef __attribute__((ext_vector_type(4))) float f32x4;

// ---------------------------------------------------------------------------
// bf16 split helpers (manual RNE, no header-struct dependence)
// ---------------------------------------------------------------------------
__device__ __forceinline__ unsigned int f2bf_bits(float f) {
    unsigned int u = __float_as_uint(f);
    return (u + 0x7FFFu + ((u >> 16) & 1u)) >> 16;
}
__device__ __forceinline__ float bfbits2f(unsigned int s) {
    return __uint_as_float(s << 16);
}
__device__ __forceinline__ void split2(float v, unsigned short& h, unsigned short& l) {
    unsigned int hb = f2bf_bits(v);
    float hf = bfbits2f(hb);
    unsigned int lb = f2bf_bits(v - hf);
    h = (unsigned short)hb; l = (unsigned short)lb;
}

__device__ __forceinline__ void gload16(const void* g, void* l) {
    __builtin_amdgcn_global_load_lds(
        (const __attribute__((address_space(1))) void*)g,
        (__attribute__((address_space(3))) void*)l, 16, 0, 0);
}

// ---------------------------------------------------------------------------
// Kernel: split fp32 -> (bf16 hi, bf16 lo), vectorized x4
// ---------------------------------------------------------------------------
__global__ __launch_bounds__(256) void split_x_kernel(
    const float* __restrict__ in, unsigned short* __restrict__ hi,
    unsigned short* __restrict__ lo, int n4)
{
    int i = blockIdx.x * 256 + threadIdx.x;
    if (i >= n4) return;
    float4 v = ((const float4*)in)[i];
    ushort4 h, l;
    split2(v.x, h.x, l.x); split2(v.y, h.y, l.y);
    split2(v.z, h.z, l.z); split2(v.w, h.w, l.w);
    ((ushort4*)hi)[i] = h;
    ((ushort4*)lo)[i] = l;
}

// 4 weight matrices [512x512] each -> hi/lo segments of 262144 elements
__global__ __launch_bounds__(256) void split_w_kernel(
    const float* __restrict__ W0, const float* __restrict__ W1,
    const float* __restrict__ W2, const float* __restrict__ W3,
    unsigned short* __restrict__ hi, unsigned short* __restrict__ lo)
{
    int w = blockIdx.y;
    const float* W = (w == 0) ? W0 : (w == 1) ? W1 : (w == 2) ? W2 : W3;
    size_t seg4 = (size_t)w * 65536;   // 262144/4
    int i = blockIdx.x * 256 + threadIdx.x;   // x4 elements
    float4 v = ((const float4*)W)[i];
    ushort4 h, l;
    split2(v.x, h.x, l.x); split2(v.y, h.y, l.y);
    split2(v.z, h.z, l.z); split2(v.w, h.w, l.w);
    ((ushort4*)hi)[seg4 + i] = h;
    ((ushort4*)lo)[seg4 + i] = l;
}

// ---------------------------------------------------------------------------
// Split-bf16 MFMA GEMM:  D[b][r][c] = sum_k A[b?][r,k]*B[b?][c,k]
//   A,B given as bf16 hi/lo pairs, [rows, K] row-major, K contiguous.
//   out[(b*RA + r)*RB + c] fp32, + bias[r] (biasOnCol=0) or bias[c] (=1),
//   + optional rpb[r*RB + c].
// 128x128 tile, BK=32, 256 thr (4 waves 2x2, each 64x64 = 4x4 frags 16x16).
// Staging: global_load_lds dwordx4, linear LDS [128][32] bf16 per matrix.
// 3 MFMAs per (fi,fj) k-step: hi*hi + lo*hi + hi*lo.
// ---------------------------------------------------------------------------
__global__ __launch_bounds__(256) void gemm_split_mfma(
    const unsigned short* __restrict__ Ahi, const unsigned short* __restrict__ Alo,
    const unsigned short* __restrict__ Bhi, const unsigned short* __restrict__ Blo,
    const float* __restrict__ bias, const float* __restrict__ rpb,
    float* __restrict__ out, int RA, int RB, int Kd,
    size_t aStride, size_t bStride, int biasOnCol)
{
    __shared__ unsigned short sAh[4096];
    __shared__ unsigned short sAl[4096];
    __shared__ unsigned short sBh[4096];
    __shared__ unsigned short sBl[4096];

    const int b  = blockIdx.z;
    const int c0 = blockIdx.x * 128;
    const int r0 = blockIdx.y * 128;

    const int tid  = threadIdx.x;
    const int lane = tid & 63;
    const int wv   = tid >> 6;
    const int wr   = wv >> 1, wc = wv & 1;

    // staging: wave wv covers tile rows [wv*32, wv*32+32); two 16-row chunks.
    const size_t laneA = (size_t)(r0 + wv * 32 + (lane >> 2)) * Kd + (size_t)((lane & 3) * 8);
    const size_t laneB = (size_t)(c0 + wv * 32 + (lane >> 2)) * Kd + (size_t)((lane & 3) * 8);
    const unsigned short* gAh = Ahi + (size_t)b * aStride + laneA;
    const unsigned short* gAl = Alo + (size_t)b * aStride + laneA;
    const unsigned short* gBh = Bhi + (size_t)b * bStride + laneB;
    const unsigned short* gBl = Blo + (size_t)b * bStride + laneB;
    const size_t rowskip = (size_t)16 * Kd;

    unsigned short* lAh = &sAh[(wv * 32) * 32];
    unsigned short* lAl = &sAl[(wv * 32) * 32];
    unsigned short* lBh = &sBh[(wv * 32) * 32];
    unsigned short* lBl = &sBl[(wv * 32) * 32];

    // fragment read bases
    const int lr = lane & 15, lk = (lane >> 4) * 8;
    const unsigned short* fAh = &sAh[(wr * 64 + lr) * 32 + lk];
    const unsigned short* fAl = &sAl[(wr * 64 + lr) * 32 + lk];
    const unsigned short* fBh = &sBh[(wc * 64 + lr) * 32 + lk];
    const unsigned short* fBl = &sBl[(wc * 64 + lr) * 32 + lk];

    f32x4 acc[4][4];
#pragma unroll
    for (int i = 0; i < 4; ++i)
#pragma unroll
        for (int j = 0; j < 4; ++j) acc[i][j] = (f32x4){0.f, 0.f, 0.f, 0.f};

    for (int k0 = 0; k0 < Kd; k0 += 32) {
        gload16(gAh + k0,           lAh);
        gload16(gAh + k0 + rowskip, lAh + 512);
        gload16(gAl + k0,           lAl);
        gload16(gAl + k0 + rowskip, lAl + 512);
        gload16(gBh + k0,           lBh);
        gload16(gBh + k0 + rowskip, lBh + 512);
        gload16(gBl + k0,           lBl);
        gload16(gBl + k0 + rowskip, lBl + 512);
        __syncthreads();   // drains vmcnt -> LDS tiles complete

        bf16x8 ah[4], al[4], bh[4], bl[4];
#pragma unroll
        for (int i = 0; i < 4; ++i) {
            ah[i] = *(const bf16x8*)(fAh + i * 512);
            al[i] = *(const bf16x8*)(fAl + i * 512);
        }
#pragma unroll
        for (int j = 0; j < 4; ++j) {
            bh[j] = *(const bf16x8*)(fBh + j * 512);
            bl[j] = *(const bf16x8*)(fBl + j * 512);
        }
#pragma unroll
        for (int i = 0; i < 4; ++i)
#pragma unroll
            for (int j = 0; j < 4; ++j) {
                acc[i][j] = __builtin_amdgcn_mfma_f32_16x16x32_bf16(ah[i], bh[j], acc[i][j], 0, 0, 0);
                acc[i][j] = __builtin_amdgcn_mfma_f32_16x16x32_bf16(al[i], bh[j], acc[i][j], 0, 0, 0);
                acc[i][j] = __builtin_amdgcn_mfma_f32_16x16x32_bf16(ah[i], bl[j], acc[i][j], 0, 0, 0);
            }
        __syncthreads();   // all waves done reading before next stage
    }

    // epilogue: C/D layout col=lane&15, row=(lane>>4)*4+reg  [m89 verified]
    const int lg4 = (lane >> 4) * 4;
    float bcol[4];
#pragma unroll
    for (int fj = 0; fj < 4; ++fj)
        bcol[fj] = biasOnCol ? bias[c0 + wc * 64 + fj * 16 + lr] : 0.f;

#pragma unroll
    for (int fi = 0; fi < 4; ++fi) {
#pragma unroll
        for (int reg = 0; reg < 4; ++reg) {
            const int r = r0 + wr * 64 + fi * 16 + lg4 + reg;
            const float br = biasOnCol ? 0.f : bias[r];
            float* orow = out + ((size_t)b * RA + r) * RB + c0;
            const float* prow = rpb ? (rpb + (size_t)r * RB + c0) : nullptr;
#pragma unroll
            for (int fj = 0; fj < 4; ++fj) {
                const int c = wc * 64 + fj * 16 + lr;
                float val = acc[fi][fj][reg] + br + bcol[fj];
                if (prow) val += prow[c];
                orow[c] = val;
            }
        }
    }
}

// ---------------------------------------------------------------------------
// Fuse the two offset convs (linear, no activation between)
// ---------------------------------------------------------------------------
__global__ void comb_weights(const float* __restrict__ Woff1, const float* __restrict__ boff1,
                             const float* __restrict__ Woff2, const float* __restrict__ boff2,
                             float* __restrict__ wc)
{
    int idx = blockIdx.x * 256 + threadIdx.x;
    if (idx < GCC * KW) {
        int cp = idx / KW, t = idx - cp * KW;
        float s = 0.f;
        for (int c = 0; c < GCC; ++c)
            s = fmaf(Woff2[c], Woff1[((size_t)c * GCC + cp) * KW + t], s);
        wc[idx] = s;
    } else if (idx == GCC * KW) {
        float s = boff2[0];
        for (int c = 0; c < GCC; ++c) s = fmaf(Woff2[c], boff1[c], s);
        wc[idx] = s;
    } else if (idx == GCC * KW + 1) {
        wc[idx] = boff2[0];
    }
}

// ---------------------------------------------------------------------------
// Fused offset prediction -> iy per (bg, l)
// ---------------------------------------------------------------------------
__global__ __launch_bounds__(256) void offsets_kernel(
    const float* __restrict__ q, const float* __restrict__ wc,
    float* __restrict__ offv)
{
    __shared__ float w[GCC * KW + 2];
    for (int i = threadIdx.x; i < GCC * KW + 2; i += 256) w[i] = wc[i];
    __syncthreads();

    int bg = blockIdx.y;
    int l  = blockIdx.x * 256 + threadIdx.x;
    const float* qb = q + (size_t)bg * GCC * LL;

    float acc;
    if (l < 2) {
        acc = w[GCC * KW + 1];
    } else {
        acc = w[GCC * KW];
        if (l >= 4) {
            for (int cp = 0; cp < GCC; ++cp) {
                const float* qr = qb + (size_t)cp * LL + l - 4;
#pragma unroll
                for (int t = 0; t < KW; ++t)
                    acc = fmaf(w[cp * KW + t], qr[t], acc);
            }
        } else {
            for (int cp = 0; cp < GCC; ++cp) {
#pragma unroll
                for (int t = 0; t < KW; ++t) {
                    int ll2 = l + t - 4;
                    if (ll2 >= 0)
                        acc = fmaf(w[cp * KW + t], qb[(size_t)cp * LL + ll2], acc);
                }
            }
        }
    }
    float off = tanhf(acc) * (float)KW;
    float vg  = (float)l + off;
    float iy  = vg * ((float)LL / (float)(LL + 2 * (KW / 2) - 1)) - 0.5f;
    offv[(size_t)bg * LL + l] = iy;
}

// ---------------------------------------------------------------------------
// Bilinear gather -> xs in [B, L, C] layout, written as bf16 hi/lo pair
// ---------------------------------------------------------------------------
__global__ __launch_bounds__(256) void gather_kernel(
    const float* __restrict__ x, const float* __restrict__ offv,
    unsigned short* __restrict__ xshi, unsigned short* __restrict__ xslo)
{
    int bg = blockIdx.y;
    int b = bg >> 2, g = bg & 3;
    int l  = blockIdx.x * 8 + (threadIdx.x >> 5);
    int d4 = (threadIdx.x & 31) * 4;

    float iy = offv[(size_t)bg * LL + l];
    float fi = floorf(iy);
    float w1 = iy - fi;
    int i0 = (int)fi;
    int i1 = i0 + 1;

    const float* xb = x + (size_t)b * LL * CC + (size_t)g * GCC + d4;
    float4 v0 = make_float4(0.f, 0.f, 0.f, 0.f);
    float4 v1 = make_float4(0.f, 0.f, 0.f, 0.f);
    if (i0 >= 0 && i0 < LL) v0 = *(const float4*)(xb + (size_t)i0 * CC);
    if (i1 >= 0 && i1 < LL) v1 = *(const float4*)(xb + (size_t)i1 * CC);
    float w0 = 1.f - w1;
    float4 r = make_float4(v0.x * w0 + v1.x * w1, v0.y * w0 + v1.y * w1,
                           v0.z * w0 + v1.z * w1, v0.w * w0 + v1.w * w1);
    size_t o = ((size_t)b * LL + l) * CC + (size_t)g * GCC + d4;
    ushort4 h, lo4;
    split2(r.x, h.x, lo4.x); split2(r.y, h.y, lo4.y);
    split2(r.z, h.z, lo4.z); split2(r.w, h.w, lo4.w);
    *(ushort4*)(xshi + o) = h;
    *(ushort4*)(xslo + o) = lo4;
}

// ---------------------------------------------------------------------------
// Attention logits, split-K (fp32 vector; small op)
// ---------------------------------------------------------------------------
__global__ __launch_bounds__(64) void qk_logits(
    const float* __restrict__ q, const float* __restrict__ k,
    float* __restrict__ part)
{
    int ks = blockIdx.x, bh = blockIdx.y;
    int b = bh >> 4, h = bh & 15;
    int lane = threadIdx.x;
    int ti = lane >> 3, tj = lane & 7;
    const float* qb = q + ((size_t)b * CC + h * HCC + ti * 4) * LL;
    const float* kb = k + ((size_t)b * CC + h * HCC + tj * 4) * LL;

    float acc[4][4];
#pragma unroll
    for (int i = 0; i < 4; ++i)
#pragma unroll
        for (int j = 0; j < 4; ++j) acc[i][j] = 0.f;

    const int chunk = LL / KSPLIT;
    int l0 = ks * chunk;
    for (int l = l0; l < l0 + chunk; l += 8) {
        float4 qa[4][2], kv[4][2];
#pragma unroll
        for (int p = 0; p < 4; ++p) {
            qa[p][0] = *(const float4*)(qb + (size_t)p * LL + l);
            qa[p][1] = *(const float4*)(qb + (size_t)p * LL + l + 4);
            kv[p][0] = *(const float4*)(kb + (size_t)p * LL + l);
            kv[p][1] = *(const float4*)(kb + (size_t)p * LL + l + 4);
        }
#pragma unroll
        for (int i = 0; i < 4; ++i)
#pragma unroll
            for (int j = 0; j < 4; ++j) {
                float s = acc[i][j];
                s = fmaf(qa[i][0].x, kv[j][0].x, s);
                s = fmaf(qa[i][0].y, kv[j][0].y, s);
                s = fmaf(qa[i][0].z, kv[j][0].z, s);
                s = fmaf(qa[i][0].w, kv[j][0].w, s);
                s = fmaf(qa[i][1].x, kv[j][1].x, s);
                s = fmaf(qa[i][1].y, kv[j][1].y, s);
                s = fmaf(qa[i][1].z, kv[j][1].z, s);
                s = fmaf(qa[i][1].w, kv[j][1].w, s);
                acc[i][j] = s;
            }
    }
#pragma unroll
    for (int i = 0; i < 4; ++i)
#pragma unroll
        for (int j = 0; j < 4; ++j)
            part[(((size_t)bh * KSPLIT + ks) * HCC + ti * 4 + i) * HCC + tj * 4 + j] = acc[i][j];
}

__global__ __launch_bounds__(64) void softmax_kernel(
    const float* __restrict__ part, float* __restrict__ attn)
{
    int bh = blockIdx.x;
    int i = threadIdx.x;
    if (i >= HCC) return;
    const float SCALE = 0.044194173824159216f;  // 512^-0.5

    float lg[HCC];
    float mx = -1e30f;
#pragma unroll
    for (int j = 0; j < HCC; ++j) {
        float s = 0.f;
        for (int ks = 0; ks < KSPLIT; ++ks)
            s += part[(((size_t)bh * KSPLIT + ks) * HCC + i) * HCC + j];
        s *= SCALE;
        lg[j] = s;
        mx = fmaxf(mx, s);
    }
    float sum = 0.f;
#pragma unroll
    for (int j = 0; j < HCC; ++j) {
        float e = expf(lg[j] - mx);
        lg[j] = e;
        sum += e;
    }
    float inv = 1.f / sum;
#pragma unroll
    for (int j = 0; j < HCC; ++j)
        attn[((size_t)bh * HCC + i) * HCC + j] = lg[j] * inv;
}

// ---------------------------------------------------------------------------
// o[bh,i,l] = sum_j attn[i,j]*v[bh,j,l], written to final [B,L,C] layout as
// bf16 hi/lo pair (feeds the out-projection MFMA GEMM).
// ---------------------------------------------------------------------------
__global__ __launch_bounds__(256) void attn_v_kernel(
    const float* __restrict__ attn, const float* __restrict__ v,
    unsigned short* __restrict__ ohi, unsigned short* __restrict__ olo)
{
    int bh = blockIdx.y;
    int b = bh >> 4, h = bh & 15;
    int tid = threadIdx.x;
    int i = tid >> 3, lsub = tid & 7;

    float arow[HCC];
#pragma unroll
    for (int j = 0; j < HCC; ++j)
        arow[j] = attn[((size_t)bh * HCC + i) * HCC + j];

    const float* vb = v + ((size_t)b * CC + h * HCC) * LL;
    __shared__ float os[HCC][65];

    for (int l0 = blockIdx.x * 512; l0 < blockIdx.x * 512 + 512; l0 += 64) {
        int lbase = l0 + lsub * 8;
        float4 a0 = make_float4(0.f, 0.f, 0.f, 0.f);
        float4 a1 = make_float4(0.f, 0.f, 0.f, 0.f);
#pragma unroll 8
        for (int j = 0; j < HCC; ++j) {
            float aw = arow[j];
            float4 v0 = *(const float4*)(vb + (size_t)j * LL + lbase);
            float4 v1 = *(const float4*)(vb + (size_t)j * LL + lbase + 4);
            a0.x = fmaf(aw, v0.x, a0.x); a0.y = fmaf(aw, v0.y, a0.y);
            a0.z = fmaf(aw, v0.z, a0.z); a0.w = fmaf(aw, v0.w, a0.w);
            a1.x = fmaf(aw, v1.x, a1.x); a1.y = fmaf(aw, v1.y, a1.y);
            a1.z = fmaf(aw, v1.z, a1.z); a1.w = fmaf(aw, v1.w, a1.w);
        }
        os[i][lsub*8+0] = a0.x; os[i][lsub*8+1] = a0.y;
        os[i][lsub*8+2] = a0.z; os[i][lsub*8+3] = a0.w;
        os[i][lsub*8+4] = a1.x; os[i][lsub*8+5] = a1.y;
        os[i][lsub*8+6] = a1.z; os[i][lsub*8+7] = a1.w;
        __syncthreads();
        int i2 = tid & 31, lw = tid >> 5;
#pragma unroll
        for (int c = 0; c < 8; ++c) {
            int ll = lw * 8 + c;
            float val = os[i2][ll];
            unsigned short hbits, lbits;
            split2(val, hbits, lbits);
            size_t oidx = ((size_t)b * LL + l0 + ll) * CC + h * HCC + i2;
            ohi[oidx] = hbits;
            olo[oidx] = lbits;
        }
        __syncthreads();
    }
}

// ---------------------------------------------------------------------------
extern "C" void kernel_launch(void* const* d_in, const int* in_sizes, int n_in,
                              void* d_out, int out_size, void* d_ws, size_t ws_size,
                              hipStream_t stream)
{
    (void)in_sizes; (void)n_in; (void)out_size; (void)ws_size;
    const float* x     = (const float*)d_in[0];
    const float* Wq    = (const float*)d_in[1];
    const float* bq    = (const float*)d_in[2];
    const float* Wk    = (const float*)d_in[3];
    const float* bk    = (const float*)d_in[4];
    const float* Wv    = (const float*)d_in[5];
    const float* bv    = (const float*)d_in[6];
    const float* Woff1 = (const float*)d_in[7];
    const float* boff1 = (const float*)d_in[8];
    const float* Woff2 = (const float*)d_in[9];
    const float* boff2 = (const float*)d_in[10];
    const float* rpb   = (const float*)d_in[11];
    const float* Wout  = (const float*)d_in[12];
    const float* bout  = (const float*)d_in[13];
    float* out = (float*)d_out;

    float* ws = (float*)d_ws;
    float* q    = ws;                          // [B,C,L]  8,388,608 f
    float* kbuf = ws + 8388608;                // [B,C,L]  8,388,608 f
    float* vbuf = ws + 16777216;               // [B,C,L]  8,388,608 f
    // bf16 pair region: serves x -> xs -> o sequentially (lifetimes disjoint)
    unsigned short* dhi = (unsigned short*)(ws + 25165824);   // 8,388,608 u16
    unsigned short* dlo = (unsigned short*)(ws + 25165824 + 4194304);
    unsigned short* whi = (unsigned short*)(ws + 33554432);   // 4x262144 u16
    unsigned short* wlo = (unsigned short*)(ws + 33554432 + 524288);
    float* offv = ws + 34603008;               // [BG,L]  65,536
    float* wcmb = ws + 34668544;               // 1,024
    float* part = ws + 34669568;               // [64,16,32,32] 1,048,576
    float* attn = ws + 35718144;               // [64,32,32] 65,536
    // end: 35,783,680 floats = 143.1 MB

    const size_t NK = (size_t)LL * CC;   // 2,097,152 per-batch activation elems

    comb_weights<<<dim3(3), dim3(256), 0, stream>>>(Woff1, boff1, Woff2, boff2, wcmb);
    split_w_kernel<<<dim3(256, 4), dim3(256), 0, stream>>>(Wq, Wk, Wv, Wout, whi, wlo);
    split_x_kernel<<<dim3(8192), dim3(256), 0, stream>>>(x, dhi, dlo, 2097152);

    // q = Wq @ x^T : A=weights (shared), B=x rows (batched) -> q [B,C,L]
    gemm_split_mfma<<<dim3(32, 4, 4), dim3(256), 0, stream>>>(
        whi + 0 * 262144, wlo + 0 * 262144, dhi, dlo, bq, nullptr,
        q, CC, LL, CC, 0, NK, 0);

    offsets_kernel<<<dim3(16, 16), dim3(256), 0, stream>>>(q, wcmb, offv);
    gather_kernel<<<dim3(512, 16), dim3(256), 0, stream>>>(x, offv, dhi, dlo);

    // k = Wk @ xs^T ; v = Wv @ xs^T + rpb
    gemm_split_mfma<<<dim3(32, 4, 4), dim3(256), 0, stream>>>(
        whi + 1 * 262144, wlo + 1 * 262144, dhi, dlo, bk, nullptr,
        kbuf, CC, LL, CC, 0, NK, 0);
    gemm_split_mfma<<<dim3(32, 4, 4), dim3(256), 0, stream>>>(
        whi + 2 * 262144, wlo + 2 * 262144, dhi, dlo, bv, rpb,
        vbuf, CC, LL, CC, 0, NK, 0);

    qk_logits<<<dim3(KSPLIT, BHN), dim3(64), 0, stream>>>(q, kbuf, part);
    softmax_kernel<<<dim3(BHN), dim3(64), 0, stream>>>(part, attn);
    attn_v_kernel<<<dim3(8, BHN), dim3(256), 0, stream>>>(attn, vbuf, dhi, dlo);

    // out = o @ Wout^T + bout : A=o rows (batched), B=Wout (shared) -> [B,L,C]
    gemm_split_mfma<<<dim3(4, 32, 4), dim3(256), 0, stream>>>(
        dhi, dlo, whi + 3 * 262144, wlo + 3 * 262144, bout, nullptr,
        out, LL, CC, CC, NK, 0, 1);
}

// Round 6
// 401.496 us; speedup vs baseline: 1.9679x; 1.1597x over previous
//
#include <hip/hip_runtime.h>
#include <math.h>

// Problem constants
#define BB   4
#define LL   4096
#define CC   512
#define GG   4
#define HH   16
#define KW   5      // conv kernel / offset range factor
#define GCC  128    // C / G
#define HCC  32     // C / H
#define BGN  (BB*GG)   // 16
#define BHN  (BB*HH)   // 64
#define KSPLIT 16

typedef __attribute__((ext_vector_type(8))) __bf16 bf16x8;
typedef __attribute__((ext_vector_type(4))) float f32x4;

// ---------------------------------------------------------------------------
// bf16 split helpers (manual RNE, no header-struct dependence)
// ---------------------------------------------------------------------------
__device__ __forceinline__ unsigned int f2bf_bits(float f) {
    unsigned int u = __float_as_uint(f);
    return (u + 0x7FFFu + ((u >> 16) & 1u)) >> 16;
}
__device__ __forceinline__ float bfbits2f(unsigned int s) {
    return __uint_as_float(s << 16);
}
__device__ __forceinline__ void split2(float v, unsigned short& h, unsigned short& l) {
    unsigned int hb = f2bf_bits(v);
    float hf = bfbits2f(hb);
    unsigned int lb = f2bf_bits(v - hf);
    h = (unsigned short)hb; l = (unsigned short)lb;
}

__device__ __forceinline__ void gload16(const void* g, void* l) {
    __builtin_amdgcn_global_load_lds(
        (const __attribute__((address_space(1))) void*)g,
        (__attribute__((address_space(3))) void*)l, 16, 0, 0);
}

// ---------------------------------------------------------------------------
// split fp32 -> (bf16 hi, bf16 lo), vectorized x4
// ---------------------------------------------------------------------------
__global__ __launch_bounds__(256) void split_x_kernel(
    const float* __restrict__ in, unsigned short* __restrict__ hi,
    unsigned short* __restrict__ lo, int n4)
{
    int i = blockIdx.x * 256 + threadIdx.x;
    if (i >= n4) return;
    float4 v = ((const float4*)in)[i];
    ushort4 h, l;
    split2(v.x, h.x, l.x); split2(v.y, h.y, l.y);
    split2(v.z, h.z, l.z); split2(v.w, h.w, l.w);
    ((ushort4*)hi)[i] = h;
    ((ushort4*)lo)[i] = l;
}

// 4 weight matrices [512x512] each -> hi/lo segments of 262144 elements
__global__ __launch_bounds__(256) void split_w_kernel(
    const float* __restrict__ W0, const float* __restrict__ W1,
    const float* __restrict__ W2, const float* __restrict__ W3,
    unsigned short* __restrict__ hi, unsigned short* __restrict__ lo)
{
    int w = blockIdx.y;
    const float* W = (w == 0) ? W0 : (w == 1) ? W1 : (w == 2) ? W2 : W3;
    size_t seg4 = (size_t)w * 65536;   // 262144/4
    int i = blockIdx.x * 256 + threadIdx.x;   // x4 elements
    float4 v = ((const float4*)W)[i];
    ushort4 h, l;
    split2(v.x, h.x, l.x); split2(v.y, h.y, l.y);
    split2(v.z, h.z, l.z); split2(v.w, h.w, l.w);
    ((ushort4*)hi)[seg4 + i] = h;
    ((ushort4*)lo)[seg4 + i] = l;
}

// ---------------------------------------------------------------------------
// Split-bf16 MFMA GEMM:  D[b][r][c] = sum_k A[b?][r,k]*B[b?][c,k]
// 128x128 tile, BK=32, 256 thr (4 waves 2x2, each 64x64 = 4x4 frags 16x16).
// 3 MFMAs per (fi,fj) k-step: hi*hi + lo*hi + hi*lo.
// ---------------------------------------------------------------------------
__global__ __launch_bounds__(256) void gemm_split_mfma(
    const unsigned short* __restrict__ Ahi, const unsigned short* __restrict__ Alo,
    const unsigned short* __restrict__ Bhi, const unsigned short* __restrict__ Blo,
    const float* __restrict__ bias, const float* __restrict__ rpb,
    float* __restrict__ out, int RA, int RB, int Kd,
    size_t aStride, size_t bStride, int biasOnCol)
{
    __shared__ unsigned short sAh[4096];
    __shared__ unsigned short sAl[4096];
    __shared__ unsigned short sBh[4096];
    __shared__ unsigned short sBl[4096];

    const int b  = blockIdx.z;
    const int c0 = blockIdx.x * 128;
    const int r0 = blockIdx.y * 128;

    const int tid  = threadIdx.x;
    const int lane = tid & 63;
    const int wv   = tid >> 6;
    const int wr   = wv >> 1, wc = wv & 1;

    const size_t laneA = (size_t)(r0 + wv * 32 + (lane >> 2)) * Kd + (size_t)((lane & 3) * 8);
    const size_t laneB = (size_t)(c0 + wv * 32 + (lane >> 2)) * Kd + (size_t)((lane & 3) * 8);
    const unsigned short* gAh = Ahi + (size_t)b * aStride + laneA;
    const unsigned short* gAl = Alo + (size_t)b * aStride + laneA;
    const unsigned short* gBh = Bhi + (size_t)b * bStride + laneB;
    const unsigned short* gBl = Blo + (size_t)b * bStride + laneB;
    const size_t rowskip = (size_t)16 * Kd;

    unsigned short* lAh = &sAh[(wv * 32) * 32];
    unsigned short* lAl = &sAl[(wv * 32) * 32];
    unsigned short* lBh = &sBh[(wv * 32) * 32];
    unsigned short* lBl = &sBl[(wv * 32) * 32];

    const int lr = lane & 15, lk = (lane >> 4) * 8;
    const unsigned short* fAh = &sAh[(wr * 64 + lr) * 32 + lk];
    const unsigned short* fAl = &sAl[(wr * 64 + lr) * 32 + lk];
    const unsigned short* fBh = &sBh[(wc * 64 + lr) * 32 + lk];
    const unsigned short* fBl = &sBl[(wc * 64 + lr) * 32 + lk];

    f32x4 acc[4][4];
#pragma unroll
    for (int i = 0; i < 4; ++i)
#pragma unroll
        for (int j = 0; j < 4; ++j) acc[i][j] = (f32x4){0.f, 0.f, 0.f, 0.f};

    for (int k0 = 0; k0 < Kd; k0 += 32) {
        gload16(gAh + k0,           lAh);
        gload16(gAh + k0 + rowskip, lAh + 512);
        gload16(gAl + k0,           lAl);
        gload16(gAl + k0 + rowskip, lAl + 512);
        gload16(gBh + k0,           lBh);
        gload16(gBh + k0 + rowskip, lBh + 512);
        gload16(gBl + k0,           lBl);
        gload16(gBl + k0 + rowskip, lBl + 512);
        __syncthreads();

        bf16x8 ah[4], al[4], bh[4], bl[4];
#pragma unroll
        for (int i = 0; i < 4; ++i) {
            ah[i] = *(const bf16x8*)(fAh + i * 512);
            al[i] = *(const bf16x8*)(fAl + i * 512);
        }
#pragma unroll
        for (int j = 0; j < 4; ++j) {
            bh[j] = *(const bf16x8*)(fBh + j * 512);
            bl[j] = *(const bf16x8*)(fBl + j * 512);
        }
#pragma unroll
        for (int i = 0; i < 4; ++i)
#pragma unroll
            for (int j = 0; j < 4; ++j) {
                acc[i][j] = __builtin_amdgcn_mfma_f32_16x16x32_bf16(ah[i], bh[j], acc[i][j], 0, 0, 0);
                acc[i][j] = __builtin_amdgcn_mfma_f32_16x16x32_bf16(al[i], bh[j], acc[i][j], 0, 0, 0);
                acc[i][j] = __builtin_amdgcn_mfma_f32_16x16x32_bf16(ah[i], bl[j], acc[i][j], 0, 0, 0);
            }
        __syncthreads();
    }

    const int lg4 = (lane >> 4) * 4;
    float bcol[4];
#pragma unroll
    for (int fj = 0; fj < 4; ++fj)
        bcol[fj] = biasOnCol ? bias[c0 + wc * 64 + fj * 16 + lr] : 0.f;

#pragma unroll
    for (int fi = 0; fi < 4; ++fi) {
#pragma unroll
        for (int reg = 0; reg < 4; ++reg) {
            const int r = r0 + wr * 64 + fi * 16 + lg4 + reg;
            const float br = biasOnCol ? 0.f : bias[r];
            float* orow = out + ((size_t)b * RA + r) * RB + c0;
            const float* prow = rpb ? (rpb + (size_t)r * RB + c0) : nullptr;
#pragma unroll
            for (int fj = 0; fj < 4; ++fj) {
                const int c = wc * 64 + fj * 16 + lr;
                float val = acc[fi][fj][reg] + br + bcol[fj];
                if (prow) val += prow[c];
                orow[c] = val;
            }
        }
    }
}

// ---------------------------------------------------------------------------
// Fuse the two offset convs (linear, no activation between)
// ---------------------------------------------------------------------------
__global__ void comb_weights(const float* __restrict__ Woff1, const float* __restrict__ boff1,
                             const float* __restrict__ Woff2, const float* __restrict__ boff2,
                             float* __restrict__ wc)
{
    int idx = blockIdx.x * 256 + threadIdx.x;
    if (idx < GCC * KW) {
        int cp = idx / KW, t = idx - cp * KW;
        float s = 0.f;
        for (int c = 0; c < GCC; ++c)
            s = fmaf(Woff2[c], Woff1[((size_t)c * GCC + cp) * KW + t], s);
        wc[idx] = s;
    } else if (idx == GCC * KW) {
        float s = boff2[0];
        for (int c = 0; c < GCC; ++c) s = fmaf(Woff2[c], boff1[c], s);
        wc[idx] = s;
    } else if (idx == GCC * KW + 1) {
        wc[idx] = boff2[0];
    }
}

// ---------------------------------------------------------------------------
// Offsets stage 1: channel-split conv partials.
// grid (32 l-chunks, 16 bg, 4 cgroups), 128 threads.
// Each block: LDS-stage q[bg, cg*32 .. cg*32+31, l0-8 .. l0+127] (f4 aligned),
// then thread li computes sum_{cp<32, t<5} w*q -> part[cg][bg][l0+li].
// ---------------------------------------------------------------------------
#define OLT 128
__global__ __launch_bounds__(128) void offsets_part_kernel(
    const float* __restrict__ q, const float* __restrict__ wc,
    float* __restrict__ part)
{
    __shared__ float sq[32][140];   // cols 0..135 used; pos = l0-8+col
    __shared__ float sw[32 * KW];

    const int l0 = blockIdx.x * OLT;
    const int bg = blockIdx.y;
    const int cg = blockIdx.z;
    const int tid = threadIdx.x;

    const float* qb = q + ((size_t)bg * GCC + cg * 32) * LL;

    for (int i = tid; i < 32 * KW; i += 128) sw[i] = wc[cg * 32 * KW + i];

    // stage: row = tid>>2 handles 34 float4's with 4 threads
    {
        const int row = tid >> 2;
        const int l4  = tid & 3;
        const float* qrow = qb + (size_t)row * LL + l0 - 8;
        for (int j = l4; j < 34; j += 4) {
            int idx = j * 4;
            float4 v;
            if (l0 - 8 + idx >= 0) v = *(const float4*)(qrow + idx);
            else v = make_float4(0.f, 0.f, 0.f, 0.f);
            *(float4*)&sq[row][idx] = v;
        }
    }
    __syncthreads();

    const int li = tid;
    float acc = 0.f;
#pragma unroll
    for (int cp = 0; cp < 32; ++cp) {
        const float* r  = &sq[cp][li + 4];
        const float* wr = &sw[cp * KW];
        acc = fmaf(wr[0], r[0], acc);
        acc = fmaf(wr[1], r[1], acc);
        acc = fmaf(wr[2], r[2], acc);
        acc = fmaf(wr[3], r[3], acc);
        acc = fmaf(wr[4], r[4], acc);
    }
    part[((size_t)cg * BGN + bg) * LL + l0 + li] = acc;
}

// ---------------------------------------------------------------------------
// Offsets stage 2: combine partials, bias/padding cases, tanh -> iy
// ---------------------------------------------------------------------------
__global__ __launch_bounds__(256) void offsets_finish_kernel(
    const float* __restrict__ part, const float* __restrict__ wc,
    float* __restrict__ offv)
{
    int i = blockIdx.x * 256 + threadIdx.x;    // over BGN*LL
    int bg = i >> 12;
    int l  = i & (LL - 1);
    float acc;
    if (l < 2) {
        acc = wc[GCC * KW + 1];                 // conv1 zero-padding region
    } else {
        acc = wc[GCC * KW]
            + part[((size_t)0 * BGN + bg) * LL + l]
            + part[((size_t)1 * BGN + bg) * LL + l]
            + part[((size_t)2 * BGN + bg) * LL + l]
            + part[((size_t)3 * BGN + bg) * LL + l];
    }
    float off = tanhf(acc) * (float)KW;
    float vg  = (float)l + off;
    float iy  = vg * ((float)LL / (float)(LL + 2 * (KW / 2) - 1)) - 0.5f;
    offv[(size_t)bg * LL + l] = iy;
}

// ---------------------------------------------------------------------------
// Bilinear gather -> xs in [B, L, C] layout, written as bf16 hi/lo pair
// ---------------------------------------------------------------------------
__global__ __launch_bounds__(256) void gather_kernel(
    const float* __restrict__ x, const float* __restrict__ offv,
    unsigned short* __restrict__ xshi, unsigned short* __restrict__ xslo)
{
    int bg = blockIdx.y;
    int b = bg >> 2, g = bg & 3;
    int l  = blockIdx.x * 8 + (threadIdx.x >> 5);
    int d4 = (threadIdx.x & 31) * 4;

    float iy = offv[(size_t)bg * LL + l];
    float fi = floorf(iy);
    float w1 = iy - fi;
    int i0 = (int)fi;
    int i1 = i0 + 1;

    const float* xb = x + (size_t)b * LL * CC + (size_t)g * GCC + d4;
    float4 v0 = make_float4(0.f, 0.f, 0.f, 0.f);
    float4 v1 = make_float4(0.f, 0.f, 0.f, 0.f);
    if (i0 >= 0 && i0 < LL) v0 = *(const float4*)(xb + (size_t)i0 * CC);
    if (i1 >= 0 && i1 < LL) v1 = *(const float4*)(xb + (size_t)i1 * CC);
    float w0 = 1.f - w1;
    float4 r = make_float4(v0.x * w0 + v1.x * w1, v0.y * w0 + v1.y * w1,
                           v0.z * w0 + v1.z * w1, v0.w * w0 + v1.w * w1);
    size_t o = ((size_t)b * LL + l) * CC + (size_t)g * GCC + d4;
    ushort4 h, lo4;
    split2(r.x, h.x, lo4.x); split2(r.y, h.y, lo4.y);
    split2(r.z, h.z, lo4.z); split2(r.w, h.w, lo4.w);
    *(ushort4*)(xshi + o) = h;
    *(ushort4*)(xslo + o) = lo4;
}

// ---------------------------------------------------------------------------
// Attention logits, split-K (fp32 vector; small op)
// ---------------------------------------------------------------------------
__global__ __launch_bounds__(64) void qk_logits(
    const float* __restrict__ q, const float* __restrict__ k,
    float* __restrict__ part)
{
    int ks = blockIdx.x, bh = blockIdx.y;
    int b = bh >> 4, h = bh & 15;
    int lane = threadIdx.x;
    int ti = lane >> 3, tj = lane & 7;
    const float* qb = q + ((size_t)b * CC + h * HCC + ti * 4) * LL;
    const float* kb = k + ((size_t)b * CC + h * HCC + tj * 4) * LL;

    float acc[4][4];
#pragma unroll
    for (int i = 0; i < 4; ++i)
#pragma unroll
        for (int j = 0; j < 4; ++j) acc[i][j] = 0.f;

    const int chunk = LL / KSPLIT;
    int l0 = ks * chunk;
    for (int l = l0; l < l0 + chunk; l += 8) {
        float4 qa[4][2], kv[4][2];
#pragma unroll
        for (int p = 0; p < 4; ++p) {
            qa[p][0] = *(const float4*)(qb + (size_t)p * LL + l);
            qa[p][1] = *(const float4*)(qb + (size_t)p * LL + l + 4);
            kv[p][0] = *(const float4*)(kb + (size_t)p * LL + l);
            kv[p][1] = *(const float4*)(kb + (size_t)p * LL + l + 4);
        }
#pragma unroll
        for (int i = 0; i < 4; ++i)
#pragma unroll
            for (int j = 0; j < 4; ++j) {
                float s = acc[i][j];
                s = fmaf(qa[i][0].x, kv[j][0].x, s);
                s = fmaf(qa[i][0].y, kv[j][0].y, s);
                s = fmaf(qa[i][0].z, kv[j][0].z, s);
                s = fmaf(qa[i][0].w, kv[j][0].w, s);
                s = fmaf(qa[i][1].x, kv[j][1].x, s);
                s = fmaf(qa[i][1].y, kv[j][1].y, s);
                s = fmaf(qa[i][1].z, kv[j][1].z, s);
                s = fmaf(qa[i][1].w, kv[j][1].w, s);
                acc[i][j] = s;
            }
    }
#pragma unroll
    for (int i = 0; i < 4; ++i)
#pragma unroll
        for (int j = 0; j < 4; ++j)
            part[(((size_t)bh * KSPLIT + ks) * HCC + ti * 4 + i) * HCC + tj * 4 + j] = acc[i][j];
}

__global__ __launch_bounds__(64) void softmax_kernel(
    const float* __restrict__ part, float* __restrict__ attn)
{
    int bh = blockIdx.x;
    int i = threadIdx.x;
    if (i >= HCC) return;
    const float SCALE = 0.044194173824159216f;  // 512^-0.5

    float lg[HCC];
    float mx = -1e30f;
#pragma unroll
    for (int j = 0; j < HCC; ++j) {
        float s = 0.f;
        for (int ks = 0; ks < KSPLIT; ++ks)
            s += part[(((size_t)bh * KSPLIT + ks) * HCC + i) * HCC + j];
        s *= SCALE;
        lg[j] = s;
        mx = fmaxf(mx, s);
    }
    float sum = 0.f;
#pragma unroll
    for (int j = 0; j < HCC; ++j) {
        float e = expf(lg[j] - mx);
        lg[j] = e;
        sum += e;
    }
    float inv = 1.f / sum;
#pragma unroll
    for (int j = 0; j < HCC; ++j)
        attn[((size_t)bh * HCC + i) * HCC + j] = lg[j] * inv;
}

// ---------------------------------------------------------------------------
// o[bh,i,l] = sum_j attn[i,j]*v[bh,j,l], -> final [B,L,C] layout as bf16 pair
// ---------------------------------------------------------------------------
__global__ __launch_bounds__(256) void attn_v_kernel(
    const float* __restrict__ attn, const float* __restrict__ v,
    unsigned short* __restrict__ ohi, unsigned short* __restrict__ olo)
{
    int bh = blockIdx.y;
    int b = bh >> 4, h = bh & 15;
    int tid = threadIdx.x;
    int i = tid >> 3, lsub = tid & 7;

    float arow[HCC];
#pragma unroll
    for (int j = 0; j < HCC; ++j)
        arow[j] = attn[((size_t)bh * HCC + i) * HCC + j];

    const float* vb = v + ((size_t)b * CC + h * HCC) * LL;
    __shared__ float os[HCC][65];

    for (int l0 = blockIdx.x * 512; l0 < blockIdx.x * 512 + 512; l0 += 64) {
        int lbase = l0 + lsub * 8;
        float4 a0 = make_float4(0.f, 0.f, 0.f, 0.f);
        float4 a1 = make_float4(0.f, 0.f, 0.f, 0.f);
#pragma unroll 8
        for (int j = 0; j < HCC; ++j) {
            float aw = arow[j];
            float4 v0 = *(const float4*)(vb + (size_t)j * LL + lbase);
            float4 v1 = *(const float4*)(vb + (size_t)j * LL + lbase + 4);
            a0.x = fmaf(aw, v0.x, a0.x); a0.y = fmaf(aw, v0.y, a0.y);
            a0.z = fmaf(aw, v0.z, a0.z); a0.w = fmaf(aw, v0.w, a0.w);
            a1.x = fmaf(aw, v1.x, a1.x); a1.y = fmaf(aw, v1.y, a1.y);
            a1.z = fmaf(aw, v1.z, a1.z); a1.w = fmaf(aw, v1.w, a1.w);
        }
        os[i][lsub*8+0] = a0.x; os[i][lsub*8+1] = a0.y;
        os[i][lsub*8+2] = a0.z; os[i][lsub*8+3] = a0.w;
        os[i][lsub*8+4] = a1.x; os[i][lsub*8+5] = a1.y;
        os[i][lsub*8+6] = a1.z; os[i][lsub*8+7] = a1.w;
        __syncthreads();
        int i2 = tid & 31, lw = tid >> 5;
#pragma unroll
        for (int c = 0; c < 8; ++c) {
            int ll = lw * 8 + c;
            float val = os[i2][ll];
            unsigned short hbits, lbits;
            split2(val, hbits, lbits);
            size_t oidx = ((size_t)b * LL + l0 + ll) * CC + h * HCC + i2;
            ohi[oidx] = hbits;
            olo[oidx] = lbits;
        }
        __syncthreads();
    }
}

// ---------------------------------------------------------------------------
extern "C" void kernel_launch(void* const* d_in, const int* in_sizes, int n_in,
                              void* d_out, int out_size, void* d_ws, size_t ws_size,
                              hipStream_t stream)
{
    (void)in_sizes; (void)n_in; (void)out_size; (void)ws_size;
    const float* x     = (const float*)d_in[0];
    const float* Wq    = (const float*)d_in[1];
    const float* bq    = (const float*)d_in[2];
    const float* Wk    = (const float*)d_in[3];
    const float* bk    = (const float*)d_in[4];
    const float* Wv    = (const float*)d_in[5];
    const float* bv    = (const float*)d_in[6];
    const float* Woff1 = (const float*)d_in[7];
    const float* boff1 = (const float*)d_in[8];
    const float* Woff2 = (const float*)d_in[9];
    const float* boff2 = (const float*)d_in[10];
    const float* rpb   = (const float*)d_in[11];
    const float* Wout  = (const float*)d_in[12];
    const float* bout  = (const float*)d_in[13];
    float* out = (float*)d_out;

    float* ws = (float*)d_ws;
    float* q    = ws;                          // [B,C,L]  8,388,608 f
    float* kbuf = ws + 8388608;                // [B,C,L]  8,388,608 f
    float* vbuf = ws + 16777216;               // [B,C,L]  8,388,608 f
    unsigned short* dhi = (unsigned short*)(ws + 25165824);   // 8,388,608 u16
    unsigned short* dlo = (unsigned short*)(ws + 25165824 + 4194304);
    unsigned short* whi = (unsigned short*)(ws + 33554432);   // 4x262144 u16
    unsigned short* wlo = (unsigned short*)(ws + 33554432 + 524288);
    float* offv = ws + 34603008;               // [BG,L]  65,536
    float* wcmb = ws + 34668544;               // 1,024
    float* part = ws + 34669568;               // [64,16,32,32] 1,048,576 (also offsets partials)
    float* attn = ws + 35718144;               // [64,32,32] 65,536

    const size_t NK = (size_t)LL * CC;   // per-batch activation elems

    comb_weights<<<dim3(3), dim3(256), 0, stream>>>(Woff1, boff1, Woff2, boff2, wcmb);
    split_w_kernel<<<dim3(256, 4), dim3(256), 0, stream>>>(Wq, Wk, Wv, Wout, whi, wlo);
    split_x_kernel<<<dim3(8192), dim3(256), 0, stream>>>(x, dhi, dlo, 2097152);

    // q = Wq @ x^T -> [B,C,L]
    gemm_split_mfma<<<dim3(32, 4, 4), dim3(256), 0, stream>>>(
        whi + 0 * 262144, wlo + 0 * 262144, dhi, dlo, bq, nullptr,
        q, CC, LL, CC, 0, NK, 0);

    // offset prediction (two-stage, parallel)
    offsets_part_kernel<<<dim3(32, 16, 4), dim3(128), 0, stream>>>(q, wcmb, part);
    offsets_finish_kernel<<<dim3(256), dim3(256), 0, stream>>>(part, wcmb, offv);
    gather_kernel<<<dim3(512, 16), dim3(256), 0, stream>>>(x, offv, dhi, dlo);

    // k = Wk @ xs^T ; v = Wv @ xs^T + rpb
    gemm_split_mfma<<<dim3(32, 4, 4), dim3(256), 0, stream>>>(
        whi + 1 * 262144, wlo + 1 * 262144, dhi, dlo, bk, nullptr,
        kbuf, CC, LL, CC, 0, NK, 0);
    gemm_split_mfma<<<dim3(32, 4, 4), dim3(256), 0, stream>>>(
        whi + 2 * 262144, wlo + 2 * 262144, dhi, dlo, bv, rpb,
        vbuf, CC, LL, CC, 0, NK, 0);

    qk_logits<<<dim3(KSPLIT, BHN), dim3(64), 0, stream>>>(q, kbuf, part);
    softmax_kernel<<<dim3(BHN), dim3(64), 0, stream>>>(part, attn);
    attn_v_kernel<<<dim3(8, BHN), dim3(256), 0, stream>>>(attn, vbuf, dhi, dlo);

    // out = o @ Wout^T + bout -> [B,L,C]
    gemm_split_mfma<<<dim3(4, 32, 4), dim3(256), 0, stream>>>(
        dhi, dlo, whi + 3 * 262144, wlo + 3 * 262144, bout, nullptr,
        out, LL, CC, CC, NK, 0, 1);
}